// Round 2
// baseline (133.591 us; speedup 1.0000x reference)
//
#include <hip/hip_runtime.h>
#include <math.h>

#define NS   8      // samples
#define CC   256    // input channels
#define PP   961    // H*W
#define MM   7688   // NS*PP nodes
#define MP   7744   // MM padded to 64
#define HID  512
#define OUTC 256

typedef _Float16 h16;
using half8   = __attribute__((ext_vector_type(8))) _Float16;
using floatx4 = __attribute__((ext_vector_type(4))) float;

#define AS1 __attribute__((address_space(1)))
#define AS3 __attribute__((address_space(3)))

// deg = 963 for b in {0,7}, 964 otherwise; dinv = deg^-0.5
__device__ __forceinline__ float dinv_of(int b) {
    return (b == 0 || b == NS - 1) ? 0.0322245515f : 0.0322078318f;
}

// K1: G1[(b*PP+p)*CC + c] = db^2*(S1[b,c] + x[b,c,p]) + db*(d(b-1)*x[b-1,c,p] + d(b+1)*x[b+1,c,p])
// S1[b,c] (colsum over p of x[b,c,:]) computed per-block for its own 32 c's
// (redundant across the 31 p-tiles; L2/L3-warm). Also zeroes SY (pt==0,ct==0).
__global__ void build_g1(const float* __restrict__ x, h16* __restrict__ G1,
                         float* __restrict__ SY) {
    int pt = blockIdx.x, ct = blockIdx.y, b = blockIdx.z;
    int p0 = pt * 32, c0 = ct * 32;
    if (pt == 0 && ct == 0) SY[b * OUTC + threadIdx.x] = 0.f;

    // phase 0: per-block column sums for c in [c0, c0+32)
    __shared__ float sS1[32];
    int wave = threadIdx.x >> 6, lane = threadIdx.x & 63;
    #pragma unroll
    for (int rr = 0; rr < 8; ++rr) {
        int i = wave * 8 + rr;
        const float* src = x + ((size_t)b * CC + c0 + i) * PP;
        float s = 0.f;
        for (int k = lane; k < PP; k += 64) s += src[k];
        #pragma unroll
        for (int off = 32; off; off >>= 1) s += __shfl_xor(s, off);
        if (lane == 0) sS1[i] = s;
    }
    __syncthreads();

    float db  = dinv_of(b);
    float wm  = (b > 0)      ? db * dinv_of(b - 1) : 0.f;
    float wp  = (b < NS - 1) ? db * dinv_of(b + 1) : 0.f;
    float db2 = db * db;
    __shared__ float t[32][33];
    int j = threadIdx.x & 31, i0 = threadIdx.x >> 5;
    int p = p0 + j;
    bool pv = (p < PP);
    #pragma unroll
    for (int r = 0; r < 4; ++r) {
        int i = i0 + r * 8;
        int c = c0 + i;
        float v = 0.f;
        if (pv) {
            size_t base = ((size_t)b * CC + c) * PP + p;
            float xb = x[base];
            float xm = (b > 0)      ? x[base - (size_t)CC * PP] : 0.f;
            float xp = (b < NS - 1) ? x[base + (size_t)CC * PP] : 0.f;
            v = db2 * (sS1[i] + xb) + wm * xm + wp * xp;
        }
        t[i][j] = v;
    }
    __syncthreads();
    int ii = threadIdx.x & 31, jj0 = threadIdx.x >> 5;
    #pragma unroll
    for (int r = 0; r < 4; ++r) {
        int jj = jj0 + r * 8;
        int pw = p0 + jj;
        if (pw < PP)
            G1[((size_t)b * PP + pw) * CC + c0 + ii] = (h16)t[ii][jj];
    }
}

// K2/K3: MFMA GEMM, 64x64 tile, BK=64, XOR-swizzled LDS chunks, fp16 in / fp32 acc.
// B ([Nc][KD] f32, torch Linear layout) is converted f32->f16 ONCE per block and
// kept LDS-resident for all K-steps; only A streams via global_load_lds with the
// proven single-buffer 2-barrier K-loop (2 loads/step).
// ACT: v = lrelu(acc + bias). DO_SUM: per-sample column sums of raw v -> atomicAdd SY.
template<int KD, bool ACT, bool DO_SUM, typename OutT>
__global__ __launch_bounds__(256) void mfma_gemm(
    const h16* __restrict__ A,     // [MP][KD] f16
    const float* __restrict__ Bf,  // [Nc][KD] f32
    const float* __restrict__ bias,
    OutT* __restrict__ C,          // [M][Nc]
    float* __restrict__ SY,        // [NS][Nc] (used when DO_SUM)
    int M, int Nc)
{
    constexpr int NT = KD / 64;
    __shared__ __align__(16) h16 As[64 * 64];          //  8 KB
    __shared__ __align__(16) h16 Bs[NT][64 * 64];      // 32/64 KB
    int tid = threadIdx.x, wave = tid >> 6, lane = tid & 63;
    int m0 = blockIdx.x * 64, n0 = blockIdx.y * 64;

    // one-time B staging: 512 chunk-tasks per 64x64 tile, 2 per thread.
    // LDS slot s of row r holds global chunk s^(r&7) (same swizzle as As).
    #pragma unroll
    for (int t = 0; t < NT; ++t) {
        #pragma unroll
        for (int it = 0; it < 2; ++it) {
            int task = it * 256 + tid;
            int r = task >> 3, c = task & 7;
            const float* src = Bf + (size_t)(n0 + r) * KD + t * 64 + c * 8;
            float4 v0 = *(const float4*)(src);
            float4 v1 = *(const float4*)(src + 4);
            half8 h = { (h16)v0.x, (h16)v0.y, (h16)v0.z, (h16)v0.w,
                        (h16)v1.x, (h16)v1.y, (h16)v1.z, (h16)v1.w };
            *(half8*)&Bs[t][r * 64 + ((c ^ (r & 7)) * 8)] = h;
        }
    }

    // A staging: per instr, 8 rows x 8 chunks(16B); lane l -> row +(l>>3), slot l&7,
    // fetches global chunk (l&7)^(l>>3) so LDS slot s of row r holds chunk s^(r&7).
    int sro = lane >> 3;
    int sch = (lane & 7) ^ sro;
    const h16* ga0 = A + (size_t)(m0 + wave * 16 + sro) * KD + sch * 8;
    h16* la0 = &As[(wave * 16) * 64];
    h16* la1 = &As[(wave * 16 + 8) * 64];
    int fr = lane & 15, fq = lane >> 4;
    floatx4 acc[4] = {{0.f,0.f,0.f,0.f},{0.f,0.f,0.f,0.f},{0.f,0.f,0.f,0.f},{0.f,0.f,0.f,0.f}};

    #pragma unroll
    for (int t = 0; t < NT; ++t) {
        __builtin_amdgcn_global_load_lds((const AS1 void*)(const void*)(ga0 + t * 64),
                                         (AS3 void*)(void*)la0, 16, 0, 0);
        __builtin_amdgcn_global_load_lds((const AS1 void*)(const void*)(ga0 + 8 * KD + t * 64),
                                         (AS3 void*)(void*)la1, 16, 0, 0);
        __syncthreads();   // drains A loads (and B ds_writes at t=0)
        #pragma unroll
        for (int ks = 0; ks < 2; ++ks) {
            int slot = (ks * 4 + fq) ^ (fr & 7);
            half8 bf = *(const half8*)&Bs[t][(wave * 16 + fr) * 64 + slot * 8];
            #pragma unroll
            for (int mb = 0; mb < 4; ++mb) {
                half8 af = *(const half8*)&As[(mb * 16 + fr) * 64 + slot * 8];
                acc[mb] = __builtin_amdgcn_mfma_f32_16x16x32_f16(af, bf, acc[mb], 0, 0, 0);
            }
        }
        __syncthreads();
    }
    int col = n0 + wave * 16 + fr;
    float bv = ACT ? bias[col] : 0.f;
    float s_lo = 0.f, s_hi = 0.f;
    int blo = m0 / 961;
    int mcut = (blo + 1) * 961;
    #pragma unroll
    for (int mb = 0; mb < 4; ++mb) {
        #pragma unroll
        for (int r = 0; r < 4; ++r) {
            int m = m0 + mb * 16 + fq * 4 + r;
            if (m < M) {
                float v = acc[mb][r] + bv;
                if (ACT) v = (v >= 0.f) ? v : 0.01f * v;
                C[(size_t)m * Nc + col] = (OutT)v;
                if (DO_SUM) { if (m < mcut) s_lo += v; else s_hi += v; }
            }
        }
    }
    if (DO_SUM) {
        s_lo += __shfl_xor(s_lo, 16);
        s_lo += __shfl_xor(s_lo, 32);
        s_hi += __shfl_xor(s_hi, 16);
        s_hi += __shfl_xor(s_hi, 32);
        if (fq == 0) {
            atomicAdd(&SY[blo * Nc + col], s_lo);
            int bhi = (m0 + 63) / 961;
            if (bhi != blo && bhi < NS) atomicAdd(&SY[bhi * Nc + col], s_hi);
        }
    }
}

// K4: out[o*PP+p] = max_b lrelu( b2[o] + db*( db*(SY[b,o]+Y[b,p,o]) + dm*Y[b-1,p,o] + dp*Y[b+1,p,o] ) )
__global__ void final_max(const float* __restrict__ Y, const float* __restrict__ SY,
                          const float* __restrict__ b2, float* __restrict__ out) {
    int pt = blockIdx.x, ot = blockIdx.y;
    int p0 = pt * 32, o0 = ot * 32;
    __shared__ float t[32][33];
    int i = threadIdx.x & 31, j0 = threadIdx.x >> 5;
    int o = o0 + i;
    float bias = b2[o];
    #pragma unroll
    for (int r = 0; r < 4; ++r) {
        int j = j0 + r * 8;
        int p = p0 + j;
        float vmax = -INFINITY;
        if (p < PP) {
            float y[NS];
            #pragma unroll
            for (int b = 0; b < NS; ++b)
                y[b] = Y[((size_t)b * PP + p) * OUTC + o];
            #pragma unroll
            for (int b = 0; b < NS; ++b) {
                float db = dinv_of(b);
                float a = db * (SY[b * OUTC + o] + y[b]);
                if (b > 0)      a += dinv_of(b - 1) * y[b - 1];
                if (b < NS - 1) a += dinv_of(b + 1) * y[b + 1];
                float z = db * a + bias;
                z = (z >= 0.f) ? z : 0.01f * z;
                vmax = fmaxf(vmax, z);
            }
        }
        t[j][i] = vmax;
    }
    __syncthreads();
    int jj = threadIdx.x & 31, ii0 = threadIdx.x >> 5;
    #pragma unroll
    for (int r = 0; r < 4; ++r) {
        int ii = ii0 + r * 8;
        int pw = p0 + jj;
        if (pw < PP)
            out[(size_t)(o0 + ii) * PP + pw] = t[jj][ii];
    }
}

extern "C" void kernel_launch(void* const* d_in, const int* in_sizes, int n_in,
                              void* d_out, int out_size, void* d_ws, size_t ws_size,
                              hipStream_t stream) {
    const float* x  = (const float*)d_in[0];
    const float* W1 = (const float*)d_in[1];
    const float* b1 = (const float*)d_in[2];
    const float* W2 = (const float*)d_in[3];
    const float* b2 = (const float*)d_in[4];
    float* out = (float*)d_out;
    float* ws  = (float*)d_ws;

    // workspace layout (float offsets, all 16B-aligned)
    float* SY  = ws;                        //      2,048 f (NS*OUTC)
    h16*  G1   = (h16*)(ws + 2048);         //  MP*CC  h =   991,232 f
    h16*  H1   = (h16*)(ws + 993280);       //  MP*HID h = 1,982,464 f (pad rows stay poison: finite)
    float* Y   = ws + 2975744;              //  MM*OUTC f = 1,968,128 f -> end 4,943,872 f (19.8 MB)

    build_g1<<<dim3(31, 8, NS), 256, 0, stream>>>(x, G1, SY);
    mfma_gemm<CC, true, false, h16><<<dim3(MP / 64, HID / 64), 256, 0, stream>>>(
        G1, W1, b1, H1, nullptr, MM, HID);
    mfma_gemm<HID, false, true, float><<<dim3(MP / 64, OUTC / 64), 256, 0, stream>>>(
        H1, W2, nullptr, Y, SY, MM, OUTC);
    final_max<<<dim3(31, 8), 256, 0, stream>>>(Y, SY, b2, out);
}

// Round 3
// 107.273 us; speedup vs baseline: 1.2453x; 1.2453x over previous
//
#include <hip/hip_runtime.h>
#include <math.h>

#define NS   8      // samples
#define CC   256    // input channels
#define PP   961    // H*W
#define MM   7688   // NS*PP nodes
#define MP   7744   // MM padded to 64
#define HID  512
#define OUTC 256

typedef _Float16 h16;
using half4   = __attribute__((ext_vector_type(4))) _Float16;
using half8   = __attribute__((ext_vector_type(8))) _Float16;
using floatx4 = __attribute__((ext_vector_type(4))) float;

#define AS1 __attribute__((address_space(1)))
#define AS3 __attribute__((address_space(3)))

// deg = 963 for b in {0,7}, 964 otherwise; dinv = deg^-0.5
__device__ __forceinline__ float dinv_of(int b) {
    return (b == 0 || b == NS - 1) ? 0.0322245515f : 0.0322078318f;
}

// K_A: all-independent segments in one launch (no same-launch ordering needed):
//  [0,1984):    build_g1' -- G1[(b*PP+p)*CC+c] = db^2*x[b,c,p] + wm*x[b-1,c,p] + wp*x[b+1,c,p]
//               (NO S1 term: that is re-added in GEMM1's epilogue as T1[b,h])
//  [1984,2240): W1/W2 -> fp16
//  [2240,2752): colsum_x -> S1 (wave per row, shuffle reduce)
//  [2752,2760): zero SY
__global__ void fused_prep(const float* __restrict__ x,
                           const float* __restrict__ W1, const float* __restrict__ W2,
                           h16* __restrict__ w1h, h16* __restrict__ w2h,
                           float* __restrict__ S1, h16* __restrict__ G1,
                           float* __restrict__ SY) {
    int blk = blockIdx.x, tid = threadIdx.x;
    if (blk < 1984) {
        int pt = blk % 31, rem = blk / 31;
        int ct = rem & 7, b = rem >> 3;
        int p0 = pt * 32, c0 = ct * 32;
        float db  = dinv_of(b);
        float wm  = (b > 0)      ? db * dinv_of(b - 1) : 0.f;
        float wp  = (b < NS - 1) ? db * dinv_of(b + 1) : 0.f;
        float db2 = db * db;
        __shared__ float t[32][33];
        int j = tid & 31, i0 = tid >> 5;
        int p = p0 + j;
        bool pv = (p < PP);
        #pragma unroll
        for (int r = 0; r < 4; ++r) {
            int i = i0 + r * 8;
            int c = c0 + i;
            float v = 0.f;
            if (pv) {
                size_t base = ((size_t)b * CC + c) * PP + p;
                float xb = x[base];
                float xm = (b > 0)      ? x[base - (size_t)CC * PP] : 0.f;
                float xp = (b < NS - 1) ? x[base + (size_t)CC * PP] : 0.f;
                v = db2 * xb + wm * xm + wp * xp;
            }
            t[i][j] = v;
        }
        __syncthreads();
        int ii = tid & 31, jj0 = tid >> 5;
        #pragma unroll
        for (int r = 0; r < 4; ++r) {
            int jj = jj0 + r * 8;
            int pw = p0 + jj;
            if (pw < PP)
                G1[((size_t)b * PP + pw) * CC + c0 + ii] = (h16)t[ii][jj];
        }
    } else if (blk < 2240) {
        int k = blk - 1984;
        bool second = k >= 128;
        const float* src = second ? W2 : W1;
        h16* dst = second ? w2h : w1h;
        int i = ((k & 127) * 256 + tid) * 4;
        float4 v = *(const float4*)(src + i);
        half4 h = { (h16)v.x, (h16)v.y, (h16)v.z, (h16)v.w };
        *(half4*)(dst + i) = h;
    } else if (blk < 2752) {
        int wave = tid >> 6, lane = tid & 63;
        int row = (blk - 2240) * 4 + wave;        // b*CC + c, < 2048
        const float* src = x + (size_t)row * PP;
        float s = 0.f;
        for (int i = lane; i < PP; i += 64) s += src[i];
        #pragma unroll
        for (int off = 32; off; off >>= 1) s += __shfl_xor(s, off);
        if (lane == 0) S1[row] = s;
    } else {
        int i = (blk - 2752) * 256 + tid;         // < 2048
        SY[i] = 0.f;
    }
}

// K2/K3: MFMA GEMM, 64x64 tile, BK=64, XOR-swizzled LDS chunks, fp16 in / fp32 acc.
// R0-verified single-buffer 2-barrier K-loop (untouched).
// DO_T1 (gemm1): epilogue adds T1[b,col] = db^2 * dot(S1[b,:], W1f[col,:]) to bias,
//   restoring the S1 term dropped from G1'. Computed per-lane from f32 W1/S1 (L2-hot):
//   fq-lane handles K-quarter fq*64..fq*64+63, then shfl_xor(16,32) sums quarters.
// ACT: v = lrelu(acc + bias). DO_SUM: per-sample column sums of raw v -> atomicAdd SY.
template<int KD, bool ACT, bool DO_T1, bool DO_SUM, typename OutT>
__global__ __launch_bounds__(256) void mfma_gemm(
    const h16* __restrict__ A,     // [MP][KD] f16
    const h16* __restrict__ B,     // [Nc][KD] f16 (torch Linear layout)
    const float* __restrict__ bias,
    const float* __restrict__ W1f, // [Nc][KD] f32 (DO_T1 only)
    const float* __restrict__ S1,  // [NS][KD] f32 (DO_T1 only)
    OutT* __restrict__ C,          // [M][Nc]
    float* __restrict__ SY,        // [NS][Nc] (DO_SUM only)
    int M, int Nc)
{
    __shared__ __align__(16) h16 As[64 * 64];
    __shared__ __align__(16) h16 Bs[64 * 64];
    int tid = threadIdx.x, wave = tid >> 6, lane = tid & 63;
    int m0 = blockIdx.x * 64, n0 = blockIdx.y * 64;
    // staging: per instr, 8 rows x 8 chunks(16B); lane l -> row +(l>>3), slot l&7,
    // fetches global chunk c = (l&7)^(l>>3) so LDS slot s of row r holds chunk s^(r&7).
    int sro = lane >> 3;
    int sch = (lane & 7) ^ sro;
    const h16* ga0 = A + (size_t)(m0 + wave * 16 + sro) * KD + sch * 8;
    const h16* gb0 = B + (size_t)(n0 + wave * 16 + sro) * KD + sch * 8;
    h16* la0 = &As[(wave * 16) * 64];
    h16* la1 = &As[(wave * 16 + 8) * 64];
    h16* lb0 = &Bs[(wave * 16) * 64];
    h16* lb1 = &Bs[(wave * 16 + 8) * 64];
    int fr = lane & 15, fq = lane >> 4;
    floatx4 acc[4] = {{0.f,0.f,0.f,0.f},{0.f,0.f,0.f,0.f},{0.f,0.f,0.f,0.f},{0.f,0.f,0.f,0.f}};
    for (int kk = 0; kk < KD; kk += 64) {
        __builtin_amdgcn_global_load_lds((const AS1 void*)(const void*)(ga0 + kk),
                                         (AS3 void*)(void*)la0, 16, 0, 0);
        __builtin_amdgcn_global_load_lds((const AS1 void*)(const void*)(ga0 + 8 * KD + kk),
                                         (AS3 void*)(void*)la1, 16, 0, 0);
        __builtin_amdgcn_global_load_lds((const AS1 void*)(const void*)(gb0 + kk),
                                         (AS3 void*)(void*)lb0, 16, 0, 0);
        __builtin_amdgcn_global_load_lds((const AS1 void*)(const void*)(gb0 + 8 * KD + kk),
                                         (AS3 void*)(void*)lb1, 16, 0, 0);
        __syncthreads();
        #pragma unroll
        for (int ks = 0; ks < 2; ++ks) {
            int slot = (ks * 4 + fq) ^ (fr & 7);
            half8 bf = *(const half8*)&Bs[(wave * 16 + fr) * 64 + slot * 8];
            #pragma unroll
            for (int mb = 0; mb < 4; ++mb) {
                half8 af = *(const half8*)&As[(mb * 16 + fr) * 64 + slot * 8];
                acc[mb] = __builtin_amdgcn_mfma_f32_16x16x32_f16(af, bf, acc[mb], 0, 0, 0);
            }
        }
        __syncthreads();
    }
    int col = n0 + wave * 16 + fr;
    float bv = ACT ? bias[col] : 0.f;
    int blo = m0 / 961;
    int mcut = (blo + 1) * 961;
    float t_lo = 0.f, t_hi = 0.f;
    if (DO_T1) {
        int bhiT = (m0 + 63) / 961;
        if (bhiT >= NS) bhiT = blo;              // pad-tile: value unused (m<M guard)
        const float4* wrow = (const float4*)(W1f + (size_t)col * KD + fq * 64);
        const float4* slo  = (const float4*)(S1 + (size_t)blo  * KD + fq * 64);
        const float4* shi  = (const float4*)(S1 + (size_t)bhiT * KD + fq * 64);
        #pragma unroll
        for (int i = 0; i < 16; ++i) {
            float4 w = wrow[i];
            float4 a = slo[i];
            float4 b = shi[i];
            t_lo += w.x * a.x + w.y * a.y + w.z * a.z + w.w * a.w;
            t_hi += w.x * b.x + w.y * b.y + w.z * b.z + w.w * b.w;
        }
        t_lo += __shfl_xor(t_lo, 16); t_lo += __shfl_xor(t_lo, 32);
        t_hi += __shfl_xor(t_hi, 16); t_hi += __shfl_xor(t_hi, 32);
        float dlo = dinv_of(blo);  t_lo *= dlo * dlo;
        float dhi = dinv_of(bhiT); t_hi *= dhi * dhi;
    }
    float s_lo = 0.f, s_hi = 0.f;
    #pragma unroll
    for (int mb = 0; mb < 4; ++mb) {
        #pragma unroll
        for (int r = 0; r < 4; ++r) {
            int m = m0 + mb * 16 + fq * 4 + r;
            if (m < M) {
                bool lo = (m < mcut);
                float v = acc[mb][r] + bv;
                if (DO_T1) v += lo ? t_lo : t_hi;
                if (ACT) v = (v >= 0.f) ? v : 0.01f * v;
                C[(size_t)m * Nc + col] = (OutT)v;
                if (DO_SUM) { if (lo) s_lo += v; else s_hi += v; }
            }
        }
    }
    if (DO_SUM) {
        s_lo += __shfl_xor(s_lo, 16);
        s_lo += __shfl_xor(s_lo, 32);
        s_hi += __shfl_xor(s_hi, 16);
        s_hi += __shfl_xor(s_hi, 32);
        if (fq == 0) {
            atomicAdd(&SY[blo * Nc + col], s_lo);
            int bhi = (m0 + 63) / 961;
            if (bhi != blo && bhi < NS) atomicAdd(&SY[bhi * Nc + col], s_hi);
        }
    }
}

// K4: out[o*PP+p] = max_b lrelu( b2[o] + db*( db*(SY[b,o]+Y[b,p,o]) + dm*Y[b-1,p,o] + dp*Y[b+1,p,o] ) )
__global__ void final_max(const float* __restrict__ Y, const float* __restrict__ SY,
                          const float* __restrict__ b2, float* __restrict__ out) {
    int pt = blockIdx.x, ot = blockIdx.y;
    int p0 = pt * 32, o0 = ot * 32;
    __shared__ float t[32][33];
    int i = threadIdx.x & 31, j0 = threadIdx.x >> 5;
    int o = o0 + i;
    float bias = b2[o];
    #pragma unroll
    for (int r = 0; r < 4; ++r) {
        int j = j0 + r * 8;
        int p = p0 + j;
        float vmax = -INFINITY;
        if (p < PP) {
            float y[NS];
            #pragma unroll
            for (int b = 0; b < NS; ++b)
                y[b] = Y[((size_t)b * PP + p) * OUTC + o];
            #pragma unroll
            for (int b = 0; b < NS; ++b) {
                float db = dinv_of(b);
                float a = db * (SY[b * OUTC + o] + y[b]);
                if (b > 0)      a += dinv_of(b - 1) * y[b - 1];
                if (b < NS - 1) a += dinv_of(b + 1) * y[b + 1];
                float z = db * a + bias;
                z = (z >= 0.f) ? z : 0.01f * z;
                vmax = fmaxf(vmax, z);
            }
        }
        t[j][i] = vmax;
    }
    __syncthreads();
    int jj = threadIdx.x & 31, ii0 = threadIdx.x >> 5;
    #pragma unroll
    for (int r = 0; r < 4; ++r) {
        int ii = ii0 + r * 8;
        int pw = p0 + jj;
        if (pw < PP)
            out[(size_t)(o0 + ii) * PP + pw] = t[jj][ii];
    }
}

extern "C" void kernel_launch(void* const* d_in, const int* in_sizes, int n_in,
                              void* d_out, int out_size, void* d_ws, size_t ws_size,
                              hipStream_t stream) {
    const float* x  = (const float*)d_in[0];
    const float* W1 = (const float*)d_in[1];
    const float* b1 = (const float*)d_in[2];
    const float* W2 = (const float*)d_in[3];
    const float* b2 = (const float*)d_in[4];
    float* out = (float*)d_out;
    float* ws  = (float*)d_ws;

    // workspace layout (float offsets, all 16B-aligned)
    float* S1  = ws;                        //      2,048 f
    float* SY  = ws + 2048;                 //      2,048 f (NS*OUTC)
    h16*  w1h  = (h16*)(ws + 4096);         //  131,072 h =  65,536 f
    h16*  w2h  = (h16*)(ws + 69632);        //  131,072 h
    h16*  G1   = (h16*)(ws + 135168);       //  MP*CC  h =   991,232 f
    h16*  H1   = (h16*)(ws + 1126400);      //  MP*HID h = 1,982,464 f (pad rows stay poison: finite)
    float* Y   = ws + 3108864;              //  MM*OUTC f = 1,968,128 f -> end 5,076,992 f (20.3 MB)

    fused_prep<<<2760, 256, 0, stream>>>(x, W1, W2, w1h, w2h, S1, G1, SY);
    mfma_gemm<CC, true, true, false, h16><<<dim3(MP / 64, HID / 64), 256, 0, stream>>>(
        G1, w1h, b1, W1, S1, H1, nullptr, MM, HID);
    mfma_gemm<HID, false, false, true, float><<<dim3(MP / 64, OUTC / 64), 256, 0, stream>>>(
        H1, w2h, nullptr, nullptr, nullptr, Y, SY, MM, OUTC);
    final_max<<<dim3(31, 8), 256, 0, stream>>>(Y, SY, b2, out);
}

// Round 4
// 99.867 us; speedup vs baseline: 1.3377x; 1.0742x over previous
//
#include <hip/hip_runtime.h>
#include <math.h>

#define NS   8      // samples
#define CC   256    // input channels
#define PP   961    // H*W
#define MM   7688   // NS*PP nodes
#define MP   7744   // MM padded to 64
#define HID  512
#define OUTC 256

typedef _Float16 h16;
using half4   = __attribute__((ext_vector_type(4))) _Float16;
using half8   = __attribute__((ext_vector_type(8))) _Float16;
using floatx4 = __attribute__((ext_vector_type(4))) float;

#define AS1 __attribute__((address_space(1)))
#define AS3 __attribute__((address_space(3)))

// deg = 963 for b in {0,7}, 964 otherwise; dinv = deg^-0.5
__device__ __forceinline__ float dinv_of(int b) {
    return (b == 0 || b == NS - 1) ? 0.0322245515f : 0.0322078318f;
}

// K0 prep: [0,256): convert W1/W2 -> fp16; [256,768): colsum_x -> S1 (one wave
// per row, shuffle reduce, no barriers); [768,776): zero SY
__global__ void prep(const float* __restrict__ W1, const float* __restrict__ W2,
                     h16* __restrict__ w1h, h16* __restrict__ w2h,
                     const float* __restrict__ x, float* __restrict__ S1,
                     float* __restrict__ SY) {
    int blk = blockIdx.x, tid = threadIdx.x;
    if (blk < 256) {
        bool second = blk >= 128;
        const float* src = second ? W2 : W1;
        h16* dst = second ? w2h : w1h;
        int i = ((blk & 127) * 256 + tid) * 4;
        float4 v = *(const float4*)(src + i);
        half4 h = { (h16)v.x, (h16)v.y, (h16)v.z, (h16)v.w };
        *(half4*)(dst + i) = h;
    } else if (blk < 768) {
        int wave = tid >> 6, lane = tid & 63;
        int row = (blk - 256) * 4 + wave;         // b*CC + c, < 2048
        const float* src = x + (size_t)row * PP;
        float s = 0.f;
        for (int i = lane; i < PP; i += 64) s += src[i];
        #pragma unroll
        for (int off = 32; off; off >>= 1) s += __shfl_xor(s, off);
        if (lane == 0) S1[row] = s;
    } else {
        int i = (blk - 768) * 256 + tid;          // < 2048
        SY[i] = 0.f;
    }
}

// K1: G1[(b*PP+p)*CC + c] = db^2*(S1[b,c] + x[b,c,p]) + db*(d(b-1)*x[b-1,c,p] + d(b+1)*x[b+1,c,p])
// 64c x 32p tile per block; LDS transpose; one half8 (16B) store per thread --
// lanes 0-7 cover a contiguous 128B row segment (vs 2B scalar stores before).
__global__ void build_g1(const float* __restrict__ x, const float* __restrict__ S1,
                         h16* __restrict__ G1) {
    int pt = blockIdx.x, ct = blockIdx.y, b = blockIdx.z;
    int p0 = pt * 32, c0 = ct * 64;
    float db  = dinv_of(b);
    float wm  = (b > 0)      ? db * dinv_of(b - 1) : 0.f;
    float wp  = (b < NS - 1) ? db * dinv_of(b + 1) : 0.f;
    float db2 = db * db;
    __shared__ float t[64][33];
    int j = threadIdx.x & 31, i0 = threadIdx.x >> 5;
    int p = p0 + j;
    bool pv = (p < PP);
    #pragma unroll
    for (int r = 0; r < 8; ++r) {
        int i = i0 + r * 8;
        int c = c0 + i;
        float v = 0.f;
        if (pv) {
            size_t base = ((size_t)b * CC + c) * PP + p;
            float xb = x[base];
            float xm = (b > 0)      ? x[base - (size_t)CC * PP] : 0.f;
            float xp = (b < NS - 1) ? x[base + (size_t)CC * PP] : 0.f;
            v = db2 * (S1[b * CC + c] + xb) + wm * xm + wp * xp;
        }
        t[i][j] = v;
    }
    __syncthreads();
    int chunk = threadIdx.x & 7, prow = threadIdx.x >> 3;   // 8 chunks x 32 rows
    int pw = p0 + prow;
    if (pw < PP) {
        half8 h;
        #pragma unroll
        for (int q = 0; q < 8; ++q) h[q] = (h16)t[chunk * 8 + q][prow];
        *(half8*)&G1[((size_t)b * PP + pw) * CC + c0 + chunk * 8] = h;
    }
}

// K2/K3: MFMA GEMM, 64x64 tile, BK=64, XOR-swizzled LDS chunks, fp16 in / fp32 acc.
// R0-verified single-buffer 2-barrier K-loop. UNTOUCHED.
// ACT: v = lrelu(acc + bias). DO_SUM: per-sample column sums of raw v -> atomicAdd SY.
template<int KD, bool ACT, bool DO_SUM, typename OutT>
__global__ __launch_bounds__(256) void mfma_gemm(
    const h16* __restrict__ A,    // [MP][KD]
    const h16* __restrict__ B,    // [Nc][KD]  (torch Linear layout)
    const float* __restrict__ bias,
    OutT* __restrict__ C,         // [M][Nc]
    float* __restrict__ SY,       // [NS][Nc] (used when DO_SUM)
    int M, int Nc)
{
    __shared__ __align__(16) h16 As[64 * 64];
    __shared__ __align__(16) h16 Bs[64 * 64];
    int tid = threadIdx.x, wave = tid >> 6, lane = tid & 63;
    int m0 = blockIdx.x * 64, n0 = blockIdx.y * 64;
    // staging: per instr, 8 rows x 8 chunks(16B); lane l -> row +(l>>3), slot l&7,
    // fetches global chunk c = (l&7)^(l>>3) so LDS slot s of row r holds chunk s^(r&7).
    int sro = lane >> 3;
    int sch = (lane & 7) ^ sro;
    const h16* ga0 = A + (size_t)(m0 + wave * 16 + sro) * KD + sch * 8;
    const h16* gb0 = B + (size_t)(n0 + wave * 16 + sro) * KD + sch * 8;
    h16* la0 = &As[(wave * 16) * 64];
    h16* la1 = &As[(wave * 16 + 8) * 64];
    h16* lb0 = &Bs[(wave * 16) * 64];
    h16* lb1 = &Bs[(wave * 16 + 8) * 64];
    int fr = lane & 15, fq = lane >> 4;
    floatx4 acc[4] = {{0.f,0.f,0.f,0.f},{0.f,0.f,0.f,0.f},{0.f,0.f,0.f,0.f},{0.f,0.f,0.f,0.f}};
    for (int kk = 0; kk < KD; kk += 64) {
        __builtin_amdgcn_global_load_lds((const AS1 void*)(const void*)(ga0 + kk),
                                         (AS3 void*)(void*)la0, 16, 0, 0);
        __builtin_amdgcn_global_load_lds((const AS1 void*)(const void*)(ga0 + 8 * KD + kk),
                                         (AS3 void*)(void*)la1, 16, 0, 0);
        __builtin_amdgcn_global_load_lds((const AS1 void*)(const void*)(gb0 + kk),
                                         (AS3 void*)(void*)lb0, 16, 0, 0);
        __builtin_amdgcn_global_load_lds((const AS1 void*)(const void*)(gb0 + 8 * KD + kk),
                                         (AS3 void*)(void*)lb1, 16, 0, 0);
        __syncthreads();
        #pragma unroll
        for (int ks = 0; ks < 2; ++ks) {
            int slot = (ks * 4 + fq) ^ (fr & 7);
            half8 bf = *(const half8*)&Bs[(wave * 16 + fr) * 64 + slot * 8];
            #pragma unroll
            for (int mb = 0; mb < 4; ++mb) {
                half8 af = *(const half8*)&As[(mb * 16 + fr) * 64 + slot * 8];
                acc[mb] = __builtin_amdgcn_mfma_f32_16x16x32_f16(af, bf, acc[mb], 0, 0, 0);
            }
        }
        __syncthreads();
    }
    int col = n0 + wave * 16 + fr;
    float bv = ACT ? bias[col] : 0.f;
    float s_lo = 0.f, s_hi = 0.f;
    int blo = m0 / 961;
    int mcut = (blo + 1) * 961;
    #pragma unroll
    for (int mb = 0; mb < 4; ++mb) {
        #pragma unroll
        for (int r = 0; r < 4; ++r) {
            int m = m0 + mb * 16 + fq * 4 + r;
            if (m < M) {
                float v = acc[mb][r] + bv;
                if (ACT) v = (v >= 0.f) ? v : 0.01f * v;
                C[(size_t)m * Nc + col] = (OutT)v;
                if (DO_SUM) { if (m < mcut) s_lo += v; else s_hi += v; }
            }
        }
    }
    if (DO_SUM) {
        s_lo += __shfl_xor(s_lo, 16);
        s_lo += __shfl_xor(s_lo, 32);
        s_hi += __shfl_xor(s_hi, 16);
        s_hi += __shfl_xor(s_hi, 32);
        if (fq == 0) {
            atomicAdd(&SY[blo * Nc + col], s_lo);
            int bhi = (m0 + 63) / 961;
            if (bhi != blo && bhi < NS) atomicAdd(&SY[bhi * Nc + col], s_hi);
        }
    }
}

// K4: out[o*PP+p] = max_b lrelu( b2[o] + db*( db*(SY[b,o]+Y[b,p,o]) + dm*Y[b-1,p,o] + dp*Y[b+1,p,o] ) )
__global__ void final_max(const float* __restrict__ Y, const float* __restrict__ SY,
                          const float* __restrict__ b2, float* __restrict__ out) {
    int pt = blockIdx.x, ot = blockIdx.y;
    int p0 = pt * 32, o0 = ot * 32;
    __shared__ float t[32][33];
    int i = threadIdx.x & 31, j0 = threadIdx.x >> 5;
    int o = o0 + i;
    float bias = b2[o];
    #pragma unroll
    for (int r = 0; r < 4; ++r) {
        int j = j0 + r * 8;
        int p = p0 + j;
        float vmax = -INFINITY;
        if (p < PP) {
            float y[NS];
            #pragma unroll
            for (int b = 0; b < NS; ++b)
                y[b] = Y[((size_t)b * PP + p) * OUTC + o];
            #pragma unroll
            for (int b = 0; b < NS; ++b) {
                float db = dinv_of(b);
                float a = db * (SY[b * OUTC + o] + y[b]);
                if (b > 0)      a += dinv_of(b - 1) * y[b - 1];
                if (b < NS - 1) a += dinv_of(b + 1) * y[b + 1];
                float z = db * a + bias;
                z = (z >= 0.f) ? z : 0.01f * z;
                vmax = fmaxf(vmax, z);
            }
        }
        t[j][i] = vmax;
    }
    __syncthreads();
    int jj = threadIdx.x & 31, ii0 = threadIdx.x >> 5;
    #pragma unroll
    for (int r = 0; r < 4; ++r) {
        int ii = ii0 + r * 8;
        int pw = p0 + jj;
        if (pw < PP)
            out[(size_t)(o0 + ii) * PP + pw] = t[jj][ii];
    }
}

extern "C" void kernel_launch(void* const* d_in, const int* in_sizes, int n_in,
                              void* d_out, int out_size, void* d_ws, size_t ws_size,
                              hipStream_t stream) {
    const float* x  = (const float*)d_in[0];
    const float* W1 = (const float*)d_in[1];
    const float* b1 = (const float*)d_in[2];
    const float* W2 = (const float*)d_in[3];
    const float* b2 = (const float*)d_in[4];
    float* out = (float*)d_out;
    float* ws  = (float*)d_ws;

    // workspace layout (float offsets, all 16B-aligned)
    float* S1  = ws;                        //      2,048 f
    float* SY  = ws + 2048;                 //      2,048 f (NS*OUTC)
    h16*  w1h  = (h16*)(ws + 4096);         //  131,072 h =  65,536 f
    h16*  w2h  = (h16*)(ws + 69632);        //  131,072 h
    h16*  G1   = (h16*)(ws + 135168);       //  MP*CC  h =   991,232 f
    h16*  H1   = (h16*)(ws + 1126400);      //  MP*HID h = 1,982,464 f (pad rows stay poison: finite)
    float* Y   = ws + 3108864;              //  MM*OUTC f = 1,968,128 f -> end 5,076,992 f (20.3 MB)

    prep<<<776, 256, 0, stream>>>(W1, W2, w1h, w2h, x, S1, SY);
    build_g1<<<dim3(31, 4, NS), 256, 0, stream>>>(x, S1, G1);
    mfma_gemm<CC, true, false, h16><<<dim3(MP / 64, HID / 64), 256, 0, stream>>>(
        G1, w1h, b1, H1, nullptr, MM, HID);
    mfma_gemm<HID, false, true, float><<<dim3(MP / 64, OUTC / 64), 256, 0, stream>>>(
        H1, w2h, nullptr, Y, SY, MM, OUTC);
    final_max<<<dim3(31, 8), 256, 0, stream>>>(Y, SY, b2, out);
}

// Round 5
// 98.370 us; speedup vs baseline: 1.3580x; 1.0152x over previous
//
#include <hip/hip_runtime.h>
#include <math.h>

#define NS   8      // samples
#define CC   256    // input channels
#define PP   961    // H*W
#define MM   7688   // NS*PP nodes
#define MP   7744   // MM padded to 64
#define HID  512
#define OUTC 256

typedef _Float16 h16;
using half4   = __attribute__((ext_vector_type(4))) _Float16;
using half8   = __attribute__((ext_vector_type(8))) _Float16;
using floatx4 = __attribute__((ext_vector_type(4))) float;

#define AS1 __attribute__((address_space(1)))
#define AS3 __attribute__((address_space(3)))

// deg = 963 for b in {0,7}, 964 otherwise; dinv = deg^-0.5
__device__ __forceinline__ float dinv_of(int b) {
    return (b == 0 || b == NS - 1) ? 0.0322245515f : 0.0322078318f;
}

// K0 prep: [0,256): convert W1/W2 -> fp16 (half4 store); [256,2304): colsum_x -> S1
// (R0-exact tree reduce: 2048 blocks, 4 independent unrolled loads/thread -- the
// wave-per-row variant was isolated as a ~+5us regression in R1/R4); [2304,2312): zero SY
__global__ void prep(const float* __restrict__ W1, const float* __restrict__ W2,
                     h16* __restrict__ w1h, h16* __restrict__ w2h,
                     const float* __restrict__ x, float* __restrict__ S1,
                     float* __restrict__ SY) {
    int blk = blockIdx.x, tid = threadIdx.x;
    if (blk < 256) {
        bool second = blk >= 128;
        const float* src = second ? W2 : W1;
        h16* dst = second ? w2h : w1h;
        int i = ((blk & 127) * 256 + tid) * 4;
        float4 v = *(const float4*)(src + i);
        half4 h = { (h16)v.x, (h16)v.y, (h16)v.z, (h16)v.w };
        *(half4*)(dst + i) = h;
    } else if (blk < 2304) {
        int bc = blk - 256;                       // b*CC + c
        const float* src = x + (size_t)bc * PP;
        float s = 0.f;
        for (int i = tid; i < PP; i += 256) s += src[i];
        __shared__ float red[256];
        red[tid] = s;
        __syncthreads();
        for (int off = 128; off > 0; off >>= 1) {
            if (tid < off) red[tid] += red[tid + off];
            __syncthreads();
        }
        if (tid == 0) S1[bc] = red[0];
    } else {
        int i = (blk - 2304) * 256 + tid;         // < 2048
        SY[i] = 0.f;
    }
}

// K1: G1[(b*PP+p)*CC + c] = db^2*(S1[b,c] + x[b,c,p]) + db*(d(b-1)*x[b-1,c,p] + d(b+1)*x[b+1,c,p])
// 64c x 32p tile per block; LDS transpose; one half8 (16B) store per thread --
// lanes 0-7 cover a contiguous 128B row segment (vs 2B scalar stores).
__global__ void build_g1(const float* __restrict__ x, const float* __restrict__ S1,
                         h16* __restrict__ G1) {
    int pt = blockIdx.x, ct = blockIdx.y, b = blockIdx.z;
    int p0 = pt * 32, c0 = ct * 64;
    float db  = dinv_of(b);
    float wm  = (b > 0)      ? db * dinv_of(b - 1) : 0.f;
    float wp  = (b < NS - 1) ? db * dinv_of(b + 1) : 0.f;
    float db2 = db * db;
    __shared__ float t[64][33];
    int j = threadIdx.x & 31, i0 = threadIdx.x >> 5;
    int p = p0 + j;
    bool pv = (p < PP);
    #pragma unroll
    for (int r = 0; r < 8; ++r) {
        int i = i0 + r * 8;
        int c = c0 + i;
        float v = 0.f;
        if (pv) {
            size_t base = ((size_t)b * CC + c) * PP + p;
            float xb = x[base];
            float xm = (b > 0)      ? x[base - (size_t)CC * PP] : 0.f;
            float xp = (b < NS - 1) ? x[base + (size_t)CC * PP] : 0.f;
            v = db2 * (S1[b * CC + c] + xb) + wm * xm + wp * xp;
        }
        t[i][j] = v;
    }
    __syncthreads();
    int chunk = threadIdx.x & 7, prow = threadIdx.x >> 3;   // 8 chunks x 32 rows
    int pw = p0 + prow;
    if (pw < PP) {
        half8 h;
        #pragma unroll
        for (int q = 0; q < 8; ++q) h[q] = (h16)t[chunk * 8 + q][prow];
        *(half8*)&G1[((size_t)b * PP + pw) * CC + c0 + chunk * 8] = h;
    }
}

// K2/K3: MFMA GEMM, 64x64 tile, BK=64, XOR-swizzled LDS chunks, fp16 in / fp32 acc.
// R0-verified single-buffer 2-barrier K-loop: UNTOUCHED.
// Epilogue: after the loop's final barrier (which orders all LDS reads), the 16KB
// staging LDS is reused as a padded transpose tile (stride 72 h16 / 68 f32 -> <=4-way
// bank aliasing) so C is stored as contiguous 128B row-chunks (half8/float4) instead
// of 16 scalar stores/thread.
// ACT: v = lrelu(acc + bias). DO_SUM: per-sample column sums of raw v -> atomicAdd SY.
template<int KD, bool ACT, bool DO_SUM, typename OutT>
__global__ __launch_bounds__(256) void mfma_gemm(
    const h16* __restrict__ A,    // [MP][KD]
    const h16* __restrict__ B,    // [Nc][KD]  (torch Linear layout)
    const float* __restrict__ bias,
    OutT* __restrict__ C,         // [M][Nc]
    float* __restrict__ SY,       // [NS][Nc] (used when DO_SUM)
    int M, int Nc)
{
    constexpr int EPAD = (sizeof(OutT) == 2) ? 72 : 68;   // epilogue row stride (elems), 16B-aligned
    constexpr int EPI_BYTES = 64 * EPAD * (int)sizeof(OutT);
    constexpr int SMEM_BYTES = EPI_BYTES > 16384 ? EPI_BYTES : 16384;
    __shared__ __align__(16) unsigned char smem[SMEM_BYTES];
    h16* As = (h16*)smem;                 // [64*64] during K-loop
    h16* Bs = (h16*)(smem + 8192);        // [64*64] during K-loop
    int tid = threadIdx.x, wave = tid >> 6, lane = tid & 63;
    int m0 = blockIdx.x * 64, n0 = blockIdx.y * 64;
    // staging: per instr, 8 rows x 8 chunks(16B); lane l -> row +(l>>3), slot l&7,
    // fetches global chunk c = (l&7)^(l>>3) so LDS slot s of row r holds chunk s^(r&7).
    int sro = lane >> 3;
    int sch = (lane & 7) ^ sro;
    const h16* ga0 = A + (size_t)(m0 + wave * 16 + sro) * KD + sch * 8;
    const h16* gb0 = B + (size_t)(n0 + wave * 16 + sro) * KD + sch * 8;
    h16* la0 = &As[(wave * 16) * 64];
    h16* la1 = &As[(wave * 16 + 8) * 64];
    h16* lb0 = &Bs[(wave * 16) * 64];
    h16* lb1 = &Bs[(wave * 16 + 8) * 64];
    int fr = lane & 15, fq = lane >> 4;
    floatx4 acc[4] = {{0.f,0.f,0.f,0.f},{0.f,0.f,0.f,0.f},{0.f,0.f,0.f,0.f},{0.f,0.f,0.f,0.f}};
    for (int kk = 0; kk < KD; kk += 64) {
        __builtin_amdgcn_global_load_lds((const AS1 void*)(const void*)(ga0 + kk),
                                         (AS3 void*)(void*)la0, 16, 0, 0);
        __builtin_amdgcn_global_load_lds((const AS1 void*)(const void*)(ga0 + 8 * KD + kk),
                                         (AS3 void*)(void*)la1, 16, 0, 0);
        __builtin_amdgcn_global_load_lds((const AS1 void*)(const void*)(gb0 + kk),
                                         (AS3 void*)(void*)lb0, 16, 0, 0);
        __builtin_amdgcn_global_load_lds((const AS1 void*)(const void*)(gb0 + 8 * KD + kk),
                                         (AS3 void*)(void*)lb1, 16, 0, 0);
        __syncthreads();
        #pragma unroll
        for (int ks = 0; ks < 2; ++ks) {
            int slot = (ks * 4 + fq) ^ (fr & 7);
            half8 bf = *(const half8*)&Bs[(wave * 16 + fr) * 64 + slot * 8];
            #pragma unroll
            for (int mb = 0; mb < 4; ++mb) {
                half8 af = *(const half8*)&As[(mb * 16 + fr) * 64 + slot * 8];
                acc[mb] = __builtin_amdgcn_mfma_f32_16x16x32_f16(af, bf, acc[mb], 0, 0, 0);
            }
        }
        __syncthreads();   // last iteration's barrier also orders LDS reads before epilogue reuse
    }
    int col = n0 + wave * 16 + fr;
    int cloc = wave * 16 + fr;
    float bv = ACT ? bias[col] : 0.f;
    float s_lo = 0.f, s_hi = 0.f;
    int blo = m0 / 961;
    int mcut = (blo + 1) * 961;
    OutT* Ts = (OutT*)smem;               // [64][EPAD] epilogue tile
    #pragma unroll
    for (int mb = 0; mb < 4; ++mb) {
        #pragma unroll
        for (int r = 0; r < 4; ++r) {
            int row = mb * 16 + fq * 4 + r;
            int m = m0 + row;
            float v = acc[mb][r] + bv;
            if (ACT) v = (v >= 0.f) ? v : 0.01f * v;
            Ts[row * EPAD + cloc] = (OutT)v;
            if (DO_SUM && m < M) { if (m < mcut) s_lo += v; else s_hi += v; }
        }
    }
    __syncthreads();
    {
        // thread t -> row t>>2, 16-elem chunk (t&3); wave covers 16 rows x 128B contiguous
        int row = tid >> 2, seg = tid & 3;
        int m = m0 + row;
        if (m < M) {
            const OutT* src = Ts + row * EPAD + seg * 16;
            OutT* dst = C + (size_t)m * Nc + n0 + seg * 16;
            if constexpr (sizeof(OutT) == 2) {
                *(half8*)(dst)     = *(const half8*)(src);
                *(half8*)(dst + 8) = *(const half8*)(src + 8);
            } else {
                #pragma unroll
                for (int q = 0; q < 4; ++q)
                    *(float4*)((float*)dst + q * 4) = *(const float4*)((const float*)src + q * 4);
            }
        }
    }
    if (DO_SUM) {
        s_lo += __shfl_xor(s_lo, 16);
        s_lo += __shfl_xor(s_lo, 32);
        s_hi += __shfl_xor(s_hi, 16);
        s_hi += __shfl_xor(s_hi, 32);
        if (fq == 0) {
            atomicAdd(&SY[blo * Nc + col], s_lo);
            int bhi = (m0 + 63) / 961;
            if (bhi != blo && bhi < NS) atomicAdd(&SY[bhi * Nc + col], s_hi);
        }
    }
}

// K4: out[o*PP+p] = max_b lrelu( b2[o] + db*( db*(SY[b,o]+Y[b,p,o]) + dm*Y[b-1,p,o] + dp*Y[b+1,p,o] ) )
__global__ void final_max(const float* __restrict__ Y, const float* __restrict__ SY,
                          const float* __restrict__ b2, float* __restrict__ out) {
    int pt = blockIdx.x, ot = blockIdx.y;
    int p0 = pt * 32, o0 = ot * 32;
    __shared__ float t[32][33];
    int i = threadIdx.x & 31, j0 = threadIdx.x >> 5;
    int o = o0 + i;
    float bias = b2[o];
    #pragma unroll
    for (int r = 0; r < 4; ++r) {
        int j = j0 + r * 8;
        int p = p0 + j;
        float vmax = -INFINITY;
        if (p < PP) {
            float y[NS];
            #pragma unroll
            for (int b = 0; b < NS; ++b)
                y[b] = Y[((size_t)b * PP + p) * OUTC + o];
            #pragma unroll
            for (int b = 0; b < NS; ++b) {
                float db = dinv_of(b);
                float a = db * (SY[b * OUTC + o] + y[b]);
                if (b > 0)      a += dinv_of(b - 1) * y[b - 1];
                if (b < NS - 1) a += dinv_of(b + 1) * y[b + 1];
                float z = db * a + bias;
                z = (z >= 0.f) ? z : 0.01f * z;
                vmax = fmaxf(vmax, z);
            }
        }
        t[j][i] = vmax;
    }
    __syncthreads();
    int jj = threadIdx.x & 31, ii0 = threadIdx.x >> 5;
    #pragma unroll
    for (int r = 0; r < 4; ++r) {
        int ii = ii0 + r * 8;
        int pw = p0 + jj;
        if (pw < PP)
            out[(size_t)(o0 + ii) * PP + pw] = t[jj][ii];
    }
}

extern "C" void kernel_launch(void* const* d_in, const int* in_sizes, int n_in,
                              void* d_out, int out_size, void* d_ws, size_t ws_size,
                              hipStream_t stream) {
    const float* x  = (const float*)d_in[0];
    const float* W1 = (const float*)d_in[1];
    const float* b1 = (const float*)d_in[2];
    const float* W2 = (const float*)d_in[3];
    const float* b2 = (const float*)d_in[4];
    float* out = (float*)d_out;
    float* ws  = (float*)d_ws;

    // workspace layout (float offsets, all 16B-aligned)
    float* S1  = ws;                        //      2,048 f
    float* SY  = ws + 2048;                 //      2,048 f (NS*OUTC)
    h16*  w1h  = (h16*)(ws + 4096);         //  131,072 h =  65,536 f
    h16*  w2h  = (h16*)(ws + 69632);        //  131,072 h
    h16*  G1   = (h16*)(ws + 135168);       //  MP*CC  h =   991,232 f
    h16*  H1   = (h16*)(ws + 1126400);      //  MP*HID h = 1,982,464 f (pad rows stay poison: finite)
    float* Y   = ws + 3108864;              //  MM*OUTC f = 1,968,128 f -> end 5,076,992 f (20.3 MB)

    prep<<<2312, 256, 0, stream>>>(W1, W2, w1h, w2h, x, S1, SY);
    build_g1<<<dim3(31, 4, NS), 256, 0, stream>>>(x, S1, G1);
    mfma_gemm<CC, true, false, h16><<<dim3(MP / 64, HID / 64), 256, 0, stream>>>(
        G1, w1h, b1, H1, nullptr, MM, HID);
    mfma_gemm<HID, false, true, float><<<dim3(MP / 64, OUTC / 64), 256, 0, stream>>>(
        H1, w2h, nullptr, Y, SY, MM, OUTC);
    final_max<<<dim3(31, 8), 256, 0, stream>>>(Y, SY, b2, out);
}

// Round 7
// 96.005 us; speedup vs baseline: 1.3915x; 1.0246x over previous
//
#include <hip/hip_runtime.h>
#include <math.h>

#define NS   8      // samples
#define CC   256    // input channels
#define PP   961    // H*W
#define MM   7688   // NS*PP nodes
#define MP   7744   // MM padded to 64
#define HID  512
#define OUTC 256

typedef _Float16 h16;
using half8   = __attribute__((ext_vector_type(8))) _Float16;
using floatx4 = __attribute__((ext_vector_type(4))) float;

#define AS1 __attribute__((address_space(1)))
#define AS3 __attribute__((address_space(3)))

// deg = 963 for b in {0,7}, 964 otherwise; dinv = deg^-0.5
__device__ __forceinline__ float dinv_of(int b) {
    return (b == 0 || b == NS - 1) ? 0.0322245515f : 0.0322078318f;
}

// K0 prep: [0,256): convert W1/W2 -> fp16; [256,2304): colsum_x -> S1; [2304,2312): zero SY
__global__ void prep(const float* __restrict__ W1, const float* __restrict__ W2,
                     h16* __restrict__ w1h, h16* __restrict__ w2h,
                     const float* __restrict__ x, float* __restrict__ S1,
                     float* __restrict__ SY) {
    int blk = blockIdx.x, tid = threadIdx.x;
    if (blk < 256) {
        bool second = blk >= 128;
        const float* src = second ? W2 : W1;
        h16* dst = second ? w2h : w1h;
        int i = ((blk & 127) * 256 + tid) * 4;
        float4 v = *(const float4*)(src + i);
        dst[i + 0] = (h16)v.x; dst[i + 1] = (h16)v.y;
        dst[i + 2] = (h16)v.z; dst[i + 3] = (h16)v.w;
    } else if (blk < 2304) {
        int bc = blk - 256;                       // b*CC + c
        const float* src = x + (size_t)bc * PP;
        float s = 0.f;
        for (int i = tid; i < PP; i += 256) s += src[i];
        __shared__ float red[256];
        red[tid] = s;
        __syncthreads();
        for (int off = 128; off > 0; off >>= 1) {
            if (tid < off) red[tid] += red[tid + off];
            __syncthreads();
        }
        if (tid == 0) S1[bc] = red[0];
    } else {
        int i = (blk - 2304) * 256 + tid;         // < 2048
        SY[i] = 0.f;
    }
}

// K1: G1[(b*PP+p)*CC + c] = db^2*(S1[b,c] + x[b,c,p]) + db*(d(b-1)*x[b-1,c,p] + d(b+1)*x[b+1,c,p])
__global__ void build_g1(const float* __restrict__ x, const float* __restrict__ S1,
                         h16* __restrict__ G1) {
    int pt = blockIdx.x, ct = blockIdx.y, b = blockIdx.z;
    int p0 = pt * 32, c0 = ct * 32;
    float db  = dinv_of(b);
    float wm  = (b > 0)      ? db * dinv_of(b - 1) : 0.f;
    float wp  = (b < NS - 1) ? db * dinv_of(b + 1) : 0.f;
    float db2 = db * db;
    __shared__ float t[32][33];
    int j = threadIdx.x & 31, i0 = threadIdx.x >> 5;
    int p = p0 + j;
    bool pv = (p < PP);
    #pragma unroll
    for (int r = 0; r < 4; ++r) {
        int i = i0 + r * 8;
        int c = c0 + i;
        float v = 0.f;
        if (pv) {
            size_t base = ((size_t)b * CC + c) * PP + p;
            float xb = x[base];
            float xm = (b > 0)      ? x[base - (size_t)CC * PP] : 0.f;
            float xp = (b < NS - 1) ? x[base + (size_t)CC * PP] : 0.f;
            v = db2 * (S1[b * CC + c] + xb) + wm * xm + wp * xp;
        }
        t[i][j] = v;
    }
    __syncthreads();
    int ii = threadIdx.x & 31, jj0 = threadIdx.x >> 5;
    #pragma unroll
    for (int r = 0; r < 4; ++r) {
        int jj = jj0 + r * 8;
        int pw = p0 + jj;
        if (pw < PP)
            G1[((size_t)b * PP + pw) * CC + c0 + ii] = (h16)t[ii][jj];
    }
}

// K2/K3: MFMA GEMM, 64x64 tile, BK=64, XOR-swizzled LDS chunks, fp16 in / fp32 acc.
// ACT: v = lrelu(acc + bias). DO_SUM: per-sample column sums of raw v -> atomicAdd SY.
template<int KD, bool ACT, bool DO_SUM, typename OutT>
__global__ __launch_bounds__(256) void mfma_gemm(
    const h16* __restrict__ A,    // [MP][KD]
    const h16* __restrict__ B,    // [Nc][KD]  (torch Linear layout)
    const float* __restrict__ bias,
    OutT* __restrict__ C,         // [M][Nc]
    float* __restrict__ SY,       // [NS][Nc] (used when DO_SUM)
    int M, int Nc)
{
    __shared__ __align__(16) h16 As[64 * 64];
    __shared__ __align__(16) h16 Bs[64 * 64];
    int tid = threadIdx.x, wave = tid >> 6, lane = tid & 63;
    int m0 = blockIdx.x * 64, n0 = blockIdx.y * 64;
    // staging: per instr, 8 rows x 8 chunks(16B); lane l -> row +(l>>3), slot l&7,
    // fetches global chunk c = (l&7)^(l>>3) so LDS slot s of row r holds chunk s^(r&7).
    int sro = lane >> 3;
    int sch = (lane & 7) ^ sro;
    const h16* ga0 = A + (size_t)(m0 + wave * 16 + sro) * KD + sch * 8;
    const h16* gb0 = B + (size_t)(n0 + wave * 16 + sro) * KD + sch * 8;
    h16* la0 = &As[(wave * 16) * 64];
    h16* la1 = &As[(wave * 16 + 8) * 64];
    h16* lb0 = &Bs[(wave * 16) * 64];
    h16* lb1 = &Bs[(wave * 16 + 8) * 64];
    int fr = lane & 15, fq = lane >> 4;
    floatx4 acc[4] = {{0.f,0.f,0.f,0.f},{0.f,0.f,0.f,0.f},{0.f,0.f,0.f,0.f},{0.f,0.f,0.f,0.f}};
    for (int kk = 0; kk < KD; kk += 64) {
        __builtin_amdgcn_global_load_lds((const AS1 void*)(const void*)(ga0 + kk),
                                         (AS3 void*)(void*)la0, 16, 0, 0);
        __builtin_amdgcn_global_load_lds((const AS1 void*)(const void*)(ga0 + 8 * KD + kk),
                                         (AS3 void*)(void*)la1, 16, 0, 0);
        __builtin_amdgcn_global_load_lds((const AS1 void*)(const void*)(gb0 + kk),
                                         (AS3 void*)(void*)lb0, 16, 0, 0);
        __builtin_amdgcn_global_load_lds((const AS1 void*)(const void*)(gb0 + 8 * KD + kk),
                                         (AS3 void*)(void*)lb1, 16, 0, 0);
        __syncthreads();
        #pragma unroll
        for (int ks = 0; ks < 2; ++ks) {
            int slot = (ks * 4 + fq) ^ (fr & 7);
            half8 bf = *(const half8*)&Bs[(wave * 16 + fr) * 64 + slot * 8];
            #pragma unroll
            for (int mb = 0; mb < 4; ++mb) {
                half8 af = *(const half8*)&As[(mb * 16 + fr) * 64 + slot * 8];
                acc[mb] = __builtin_amdgcn_mfma_f32_16x16x32_f16(af, bf, acc[mb], 0, 0, 0);
            }
        }
        __syncthreads();
    }
    int col = n0 + wave * 16 + fr;
    float bv = ACT ? bias[col] : 0.f;
    float s_lo = 0.f, s_hi = 0.f;
    int blo = m0 / 961;
    int mcut = (blo + 1) * 961;
    #pragma unroll
    for (int mb = 0; mb < 4; ++mb) {
        #pragma unroll
        for (int r = 0; r < 4; ++r) {
            int m = m0 + mb * 16 + fq * 4 + r;
            if (m < M) {
                float v = acc[mb][r] + bv;
                if (ACT) v = (v >= 0.f) ? v : 0.01f * v;
                C[(size_t)m * Nc + col] = (OutT)v;
                if (DO_SUM) { if (m < mcut) s_lo += v; else s_hi += v; }
            }
        }
    }
    if (DO_SUM) {
        s_lo += __shfl_xor(s_lo, 16);
        s_lo += __shfl_xor(s_lo, 32);
        s_hi += __shfl_xor(s_hi, 16);
        s_hi += __shfl_xor(s_hi, 32);
        if (fq == 0) {
            atomicAdd(&SY[blo * Nc + col], s_lo);
            int bhi = (m0 + 63) / 961;
            if (bhi != blo && bhi < NS) atomicAdd(&SY[bhi * Nc + col], s_hi);
        }
    }
}

// K4: out[o*PP+p] = max_b lrelu( b2[o] + db*( db*(SY[b,o]+Y[b,p,o]) + dm*Y[b-1,p,o] + dp*Y[b+1,p,o] ) )
__global__ void final_max(const float* __restrict__ Y, const float* __restrict__ SY,
                          const float* __restrict__ b2, float* __restrict__ out) {
    int pt = blockIdx.x, ot = blockIdx.y;
    int p0 = pt * 32, o0 = ot * 32;
    __shared__ float t[32][33];
    int i = threadIdx.x & 31, j0 = threadIdx.x >> 5;
    int o = o0 + i;
    float bias = b2[o];
    #pragma unroll
    for (int r = 0; r < 4; ++r) {
        int j = j0 + r * 8;
        int p = p0 + j;
        float vmax = -INFINITY;
        if (p < PP) {
            float y[NS];
            #pragma unroll
            for (int b = 0; b < NS; ++b)
                y[b] = Y[((size_t)b * PP + p) * OUTC + o];
            #pragma unroll
            for (int b = 0; b < NS; ++b) {
                float db = dinv_of(b);
                float a = db * (SY[b * OUTC + o] + y[b]);
                if (b > 0)      a += dinv_of(b - 1) * y[b - 1];
                if (b < NS - 1) a += dinv_of(b + 1) * y[b + 1];
                float z = db * a + bias;
                z = (z >= 0.f) ? z : 0.01f * z;
                vmax = fmaxf(vmax, z);
            }
        }
        t[j][i] = vmax;
    }
    __syncthreads();
    int jj = threadIdx.x & 31, ii0 = threadIdx.x >> 5;
    #pragma unroll
    for (int r = 0; r < 4; ++r) {
        int ii = ii0 + r * 8;
        int pw = p0 + jj;
        if (pw < PP)
            out[(size_t)(o0 + ii) * PP + pw] = t[jj][ii];
    }
}

extern "C" void kernel_launch(void* const* d_in, const int* in_sizes, int n_in,
                              void* d_out, int out_size, void* d_ws, size_t ws_size,
                              hipStream_t stream) {
    const float* x  = (const float*)d_in[0];
    const float* W1 = (const float*)d_in[1];
    const float* b1 = (const float*)d_in[2];
    const float* W2 = (const float*)d_in[3];
    const float* b2 = (const float*)d_in[4];
    float* out = (float*)d_out;
    float* ws  = (float*)d_ws;

    // workspace layout (float offsets, all 16B-aligned)
    float* S1  = ws;                        //      2,048 f
    float* SY  = ws + 2048;                 //      2,048 f (NS*OUTC)
    h16*  w1h  = (h16*)(ws + 4096);         //  131,072 h =  65,536 f
    h16*  w2h  = (h16*)(ws + 69632);        //  131,072 h
    h16*  G1   = (h16*)(ws + 135168);       //  MP*CC  h =  991,232 f
    h16*  H1   = (h16*)(ws + 1126400);      //  MP*HID h = 1,982,464 f (pad rows stay poison: finite)
    float* Y   = ws + 3108864;              //  MM*OUTC f = 1,968,128 f -> end 5,076,992 f (20.3 MB)

    prep<<<2312, 256, 0, stream>>>(W1, W2, w1h, w2h, x, S1, SY);
    build_g1<<<dim3(31, 8, NS), 256, 0, stream>>>(x, S1, G1);
    mfma_gemm<CC, true, false, h16><<<dim3(MP / 64, HID / 64), 256, 0, stream>>>(
        G1, w1h, b1, H1, nullptr, MM, HID);
    mfma_gemm<HID, false, true, float><<<dim3(MP / 64, OUTC / 64), 256, 0, stream>>>(
        H1, w2h, nullptr, Y, SY, MM, OUTC);
    final_max<<<dim3(31, 8), 256, 0, stream>>>(Y, SY, b2, out);
}